// Round 2
// baseline (157.382 us; speedup 1.0000x reference)
//
#include <hip/hip_runtime.h>
#include <hip/hip_bf16.h>

#define NB 4
#define NC 128
#define NH 128
#define NW 240
#define NE 64
#define NK 9
#define PLANE (NH*NW)        // 30720: stride between channels
#define CHW (NC*PLANE)
#define XS 244               // xs row stride in ushort (488 B: 8B-aligned, de-conflicted)
#define WS_SIDE ((size_t)NB*NH*NW*64)   // halfs per side in workspace

typedef __attribute__((ext_vector_type(8))) short short8;
typedef __attribute__((ext_vector_type(4))) float f32x4;
typedef __attribute__((ext_vector_type(2))) __fp16 fp16x2;
typedef __attribute__((ext_vector_type(8))) __fp16 fp16x8;

__device__ __forceinline__ unsigned pk2bf(float x, float y){
  __hip_bfloat162 h = __float22bfloat162_rn(make_float2(x, y));  // v_cvt_pk_bf16_f32 on gfx950
  return *(unsigned*)&h;
}
__device__ __forceinline__ unsigned short f2bf(float f){
  unsigned u = __float_as_uint(f);
  u += 0x7fffu + ((u>>16)&1u);           // RNE
  return (unsigned short)(u>>16);
}
__device__ __forceinline__ float bfl(unsigned v){ return __uint_as_float(v<<16); }
__device__ __forceinline__ float bfh(unsigned v){ return __uint_as_float(v & 0xffff0000u); }

// fp16 pack (v_cvt_pkrtz_f16_f32) — builtin returns __fp16 ext-vector
__device__ __forceinline__ unsigned pkh(float x, float y){
  fp16x2 h = __builtin_amdgcn_cvt_pkrtz(x, y);
  return __builtin_bit_cast(unsigned, h);
}
// half2 dot with f32 accumulate (v_dot2_f32_f16)
__device__ __forceinline__ float fdot2u(unsigned a, unsigned b, float c){
#if __has_builtin(__builtin_amdgcn_fdot2)
  return __builtin_amdgcn_fdot2(__builtin_bit_cast(fp16x2,a),
                                __builtin_bit_cast(fp16x2,b), c, false);
#else
  fp16x2 ha = __builtin_bit_cast(fp16x2,a), hb = __builtin_bit_cast(fp16x2,b);
  return c + (float)ha[0]*(float)hb[0] + (float)ha[1]*(float)hb[1];
#endif
}
__device__ __forceinline__ int swz(int r){ return (r ^ (r>>3)) & 7; }

// ======================================================================
// Kernel E: embed both sides. One block per (side, b, h) row.
// grid = 2*NB*NH = 1024, block = 512 (8 waves). LDS = 79,872 B -> 2 blk/CU.
// Writes normalized fp16 embeddings, layout [side][b][h][w][e], e contiguous.
// ======================================================================
__global__ __launch_bounds__(512, 4)
void embed_kernel(const float* __restrict__ xL,
                  const float* __restrict__ xR,
                  const float* __restrict__ phig,
                  unsigned short* __restrict__ ws)
{
  __shared__ __attribute__((aligned(16))) unsigned short xs[NC*XS];     // 62,464 B
  __shared__ __attribute__((aligned(16))) unsigned short phis[NE*136];  // 17,408 B

  const int tid  = threadIdx.x;
  const int lane = tid & 63;
  const int wv   = tid >> 6;
  const int bid  = blockIdx.x;
  const int side = bid >> 9;
  const int b    = (bid >> 7) & 3;
  const int h    = bid & 127;
  const float* xg = side ? xR : xL;
  unsigned short* outp = ws + (size_t)side * WS_SIDE;
  const size_t base = (size_t)b*CHW + (size_t)h*NW;
  const int pixbase = (b*NH + h)*NW;

  // ---- stage phi (fp32 -> fp16): 2048 float4 over 512 threads ----
  #pragma unroll
  for (int i = 0; i < 4; ++i) {
    int idx = i*512 + tid;
    int e = idx >> 5, q = idx & 31;
    float4 v = *(const float4*)(phig + e*128 + 4*q);
    uint2 pk; pk.x = pkh(v.x, v.y); pk.y = pkh(v.z, v.w);
    *(uint2*)&phis[e*136 + 4*q] = pk;
  }
  // ---- stage x row (coalesced along W) ----
  #pragma unroll
  for (int i = 0; i < 16; ++i) {
    int tau = i*512 + tid;
    int c = tau >> 6, s = tau & 63;
    if (s < 60) {
      float4 v = *(const float4*)(xg + base + (size_t)c*PLANE + 4*s);
      uint2 pk; pk.x = pkh(v.x, v.y); pk.y = pkh(v.z, v.w);
      *(uint2*)&xs[c*XS + 4*s] = pk;
    }
  }
  __syncthreads();

  // ---- GEMM + normalize. Wave wv owns N-tiles {wv, wv+8} (15 tiles total) ----
  const int mrow = lane & 15;
  const int kg   = lane >> 4;

  f32x4 acc[2][4];
  #pragma unroll
  for (int tt = 0; tt < 2; ++tt)
    #pragma unroll
    for (int mt = 0; mt < 4; ++mt) acc[tt][mt] = (f32x4){0.f,0.f,0.f,0.f};
  float inv[2] = {0.f, 0.f};

  #pragma unroll
  for (int tt = 0; tt < 2; ++tt) {
    int nt = wv + 8*tt;
    if (nt < 15) {
      const int col = 16*nt + mrow;
      #pragma unroll
      for (int ks = 0; ks < 4; ++ks) {
        const int r0 = 32*ks + 8*kg;
        fp16x8 bv;
        #pragma unroll
        for (int j = 0; j < 8; ++j)
          bv[j] = *(const __fp16*)&xs[(r0 + j)*XS + col];
        #pragma unroll
        for (int mt = 0; mt < 4; ++mt) {
          short8 raw = *(const short8*)&phis[(16*mt + mrow)*136 + 32*ks + 8*kg];
          fp16x8 af = __builtin_bit_cast(fp16x8, raw);
          acc[tt][mt] = __builtin_amdgcn_mfma_f32_16x16x32_f16(af, bv, acc[tt][mt], 0, 0, 0);
        }
      }
      float ss = 0.f;
      #pragma unroll
      for (int mt = 0; mt < 4; ++mt)
        #pragma unroll
        for (int r = 0; r < 4; ++r)
          ss += acc[tt][mt][r]*acc[tt][mt][r];
      ss += __shfl_xor(ss, 16, 64);
      ss += __shfl_xor(ss, 32, 64);
      inv[tt] = 1.f/(sqrtf(ss) + 1e-6f);
    }
  }
  __syncthreads();           // all xs reads done; safe to alias

  // ---- transpose through LDS (aliased over xs) for coalesced stores ----
  unsigned short* Ea = &xs[0];  // 240*64 halfs = 30,720 B <= xs size
  #pragma unroll
  for (int tt = 0; tt < 2; ++tt) {
    int nt = wv + 8*tt;
    if (nt < 15) {
      int n = 16*nt + mrow;
      #pragma unroll
      for (int mt = 0; mt < 4; ++mt) {
        int e0 = 16*mt + 4*kg;
        uint2 pk;
        pk.x = pkh(acc[tt][mt][0]*inv[tt], acc[tt][mt][1]*inv[tt]);
        pk.y = pkh(acc[tt][mt][2]*inv[tt], acc[tt][mt][3]*inv[tt]);
        int pos = n*64 + ((((e0>>3) ^ (n&7))<<3)) + (e0&7);
        *(uint2*)&Ea[pos] = pk;
      }
    }
  }
  __syncthreads();

  // ---- fully coalesced global store: 1920 uint4 ----
  #pragma unroll
  for (int i = 0; i < 4; ++i) {
    int t = i*512 + tid;
    if (t < 1920) {
      int pix = t >> 3, c4 = t & 7;
      uint4 v = *(const uint4*)&Ea[pix*64 + ((c4 ^ (pix&7))<<3)];
      *(uint4*)(outp + (size_t)(pixbase + pix)*64 + c4*8) = v;
    }
  }
}

// ======================================================================
// Kernel C: cost volume. One block per (b,h) row.
// grid = NB*NH = 512, block = 512 (8 waves). LDS = 61,440 B -> 2 blk/CU.
// 2-way e-split: thread pair (p,eh) each handles 32 of 64 e via v_dot2.
// ======================================================================
__global__ __launch_bounds__(512, 4)
void cost_kernel(const unsigned short* __restrict__ ws,
                 const float* __restrict__ d0g,
                 float* __restrict__ outg)
{
  __shared__ __attribute__((aligned(16))) unsigned short FLb[NW*64];
  __shared__ __attribute__((aligned(16))) unsigned short FRb[NW*64];

  const int tid = threadIdx.x;
  const int b   = blockIdx.x >> 7;
  const int h   = blockIdx.x & 127;
  const int pixbase = (b*NH + h)*NW;
  const unsigned short* FLg = ws;
  const unsigned short* FRg = ws + WS_SIDE;

  // ---- stage FL/FR rows (coalesced uint4), XOR-swizzled LDS layout ----
  #pragma unroll
  for (int i = 0; i < 4; ++i) {
    int t = i*512 + tid;
    if (t < 1920) {
      int pix = t >> 3, c4 = t & 7;
      uint4 v = *(const uint4*)(FLg + (size_t)(pixbase + pix)*64 + c4*8);
      *(uint4*)&FLb[pix*64 + ((c4 ^ swz(pix))<<3)] = v;
    }
  }
  #pragma unroll
  for (int i = 0; i < 4; ++i) {
    int t = i*512 + tid;
    if (t < 1920) {
      int pix = t >> 3, c4 = t & 7;
      uint4 v = *(const uint4*)(FRg + (size_t)(pixbase + pix)*64 + c4*8);
      *(uint4*)&FRb[pix*64 + ((c4 ^ swz(pix))<<3)] = v;
    }
  }
  __syncthreads();

  if (tid < 480) {
    const int p  = tid >> 1;
    const int eh = tid & 1;
    float d0v = d0g[pixbase + p];
    float xf  = (float)p - d0v;
    float x0  = floorf(xf);
    float wfr = xf - x0;
    int jb = (int)x0 - 4;

    // own half of FL[p]: 32 e = 16 half2
    unsigned fl[16];
    #pragma unroll
    for (int i = 0; i < 4; ++i) {
      int c4 = 4*eh + i;
      uint4 raw = *(const uint4*)&FLb[p*64 + ((c4 ^ swz(p))<<3)];
      fl[4*i+0]=raw.x; fl[4*i+1]=raw.y; fl[4*i+2]=raw.z; fl[4*i+3]=raw.w;
    }

    float D[10];
    #pragma unroll
    for (int t = 0; t < 10; ++t) {
      int j = jb + t;
      j = j < 0 ? 0 : (j > NW-1 ? NW-1 : j);
      float s = 0.f;
      #pragma unroll
      for (int i = 0; i < 4; ++i) {
        int c4 = 4*eh + i;
        uint4 raw = *(const uint4*)&FRb[j*64 + ((c4 ^ swz(j))<<3)];
        s = fdot2u(fl[4*i+0], raw.x, s);
        s = fdot2u(fl[4*i+1], raw.y, s);
        s = fdot2u(fl[4*i+2], raw.z, s);
        s = fdot2u(fl[4*i+3], raw.w, s);
      }
      D[t] = s;
    }
    // combine the two e-halves (partner lane = tid^1)
    #pragma unroll
    for (int t = 0; t < 10; ++t) D[t] += __shfl_xor(D[t], 1, 64);

    size_t ob = (size_t)b*NK*PLANE + (size_t)h*NW + p;
    if (eh == 0) {
      #pragma unroll
      for (int k = 0; k < 5; ++k) {
        int t0 = 8 - k;
        outg[ob + (size_t)k*PLANE] = (1.f - wfr)*D[t0] + wfr*D[t0+1];
      }
    } else {
      #pragma unroll
      for (int k = 5; k < 9; ++k) {
        int t0 = 8 - k;
        outg[ob + (size_t)k*PLANE] = (1.f - wfr)*D[t0] + wfr*D[t0+1];
      }
    }
  }
}

// ======================================================================
// Fallback: previous verified fused kernel (158 µs) — used if ws too small.
// ======================================================================
__global__ __launch_bounds__(1024, 4)
void corr_kernel(const float* __restrict__ xL,
                 const float* __restrict__ xR,
                 const float* __restrict__ d0g,
                 const float* __restrict__ phig,
                 float* __restrict__ outg)
{
  __shared__ __attribute__((aligned(16))) unsigned short xs[NC*XS];
  __shared__ __attribute__((aligned(16))) unsigned short phis[NE*136];
  __shared__ __attribute__((aligned(16))) unsigned short FLb[NW*64];
  __shared__ __attribute__((aligned(16))) unsigned short FRb[NW*64];

  const int tid  = threadIdx.x;
  const int lane = tid & 63;
  const int wv   = tid >> 6;
  const int b    = blockIdx.x >> 7;
  const int h    = blockIdx.x & 127;
  const size_t base = (size_t)b*CHW + (size_t)h*NW;

  float d0v = 0.f;
  if (tid < NW) d0v = d0g[(b*NH + h)*NW + tid];

  #pragma unroll
  for (int i = 0; i < 2; ++i) {
    int idx = i*1024 + tid;
    int e = idx >> 5, q = idx & 31;
    float4 v = *(const float4*)(phig + e*128 + 4*q);
    uint2 pk; pk.x = pk2bf(v.x, v.y); pk.y = pk2bf(v.z, v.w);
    *(uint2*)&phis[e*136 + 4*q] = pk;
  }

  #pragma unroll
  for (int i = 0; i < 8; ++i) {
    int tau = i*1024 + tid;
    int c = tau >> 6, s = tau & 63;
    if (s < 60) {
      float4 v = *(const float4*)(xL + base + (size_t)c*PLANE + 4*s);
      uint2 pk; pk.x = pk2bf(v.x, v.y); pk.y = pk2bf(v.z, v.w);
      *(uint2*)&xs[c*XS + 4*s] = pk;
    }
  }
  __syncthreads();

  const int mrow = lane & 15;
  const int kg   = lane >> 4;
  const int nt   = wv;

  auto gemm_norm = [&](unsigned short* dst) {
    f32x4 acc[4];
    #pragma unroll
    for (int mt = 0; mt < 4; ++mt) acc[mt] = (f32x4){0.f,0.f,0.f,0.f};

    if (nt < 15) {
      const int col = 16*nt + mrow;
      #pragma unroll
      for (int ks = 0; ks < 4; ++ks) {
        const int r0 = 32*ks + 8*kg;
        short8 bfv;
        #pragma unroll
        for (int j = 0; j < 8; ++j)
          bfv[j] = (short)xs[(r0 + j)*XS + col];
        #pragma unroll
        for (int mt = 0; mt < 4; ++mt) {
          short8 af = *(const short8*)&phis[(16*mt + mrow)*136 + 32*ks + 8*kg];
          acc[mt] = __builtin_amdgcn_mfma_f32_16x16x32_bf16(af, bfv, acc[mt], 0, 0, 0);
        }
      }
      float ss = 0.f;
      #pragma unroll
      for (int mt = 0; mt < 4; ++mt)
        #pragma unroll
        for (int r = 0; r < 4; ++r)
          ss += acc[mt][r]*acc[mt][r];
      ss += __shfl_xor(ss, 16, 64);
      ss += __shfl_xor(ss, 32, 64);
      float inv = 1.f/(sqrtf(ss) + 1e-6f);
      int n = 16*nt + mrow;
      #pragma unroll
      for (int mt = 0; mt < 4; ++mt) {
        int e0 = 16*mt + 4*kg;
        ushort4 pk;
        pk.x = f2bf(acc[mt][0]*inv);
        pk.y = f2bf(acc[mt][1]*inv);
        pk.z = f2bf(acc[mt][2]*inv);
        pk.w = f2bf(acc[mt][3]*inv);
        int pos = n*64 + (((e0>>3) ^ (n&7))<<3) + (e0&7);
        *(ushort4*)&dst[pos] = pk;
      }
    }
  };

  gemm_norm(FLb);
  __syncthreads();

  #pragma unroll
  for (int i = 0; i < 8; ++i) {
    int tau = i*1024 + tid;
    int c = tau >> 6, s = tau & 63;
    if (s < 60) {
      float4 v = *(const float4*)(xR + base + (size_t)c*PLANE + 4*s);
      uint2 pk; pk.x = pk2bf(v.x, v.y); pk.y = pk2bf(v.z, v.w);
      *(uint2*)&xs[c*XS + 4*s] = pk;
    }
  }
  __syncthreads();

  gemm_norm(FRb);
  __syncthreads();

  if (tid < NW) {
    const int p = tid;
    float xf  = (float)p - d0v;
    float x0  = floorf(xf);
    float wfr = xf - x0;
    int jb = (int)x0 - 4;

    float fl[64];
    #pragma unroll
    for (int c = 0; c < 8; ++c) {
      uint4 raw = *(const uint4*)&FLb[p*64 + ((c ^ (p&7))<<3)];
      fl[8*c+0]=bfl(raw.x); fl[8*c+1]=bfh(raw.x);
      fl[8*c+2]=bfl(raw.y); fl[8*c+3]=bfh(raw.y);
      fl[8*c+4]=bfl(raw.z); fl[8*c+5]=bfh(raw.z);
      fl[8*c+6]=bfl(raw.w); fl[8*c+7]=bfh(raw.w);
    }

    float D[10];
    #pragma unroll
    for (int t = 0; t < 10; ++t) {
      int j = jb + t;
      j = j < 0 ? 0 : (j > NW-1 ? NW-1 : j);
      float s = 0.f;
      #pragma unroll
      for (int c = 0; c < 8; ++c) {
        uint4 raw = *(const uint4*)&FRb[j*64 + ((c ^ (j&7))<<3)];
        s += fl[8*c+0]*bfl(raw.x) + fl[8*c+1]*bfh(raw.x)
           + fl[8*c+2]*bfl(raw.y) + fl[8*c+3]*bfh(raw.y)
           + fl[8*c+4]*bfl(raw.z) + fl[8*c+5]*bfh(raw.z)
           + fl[8*c+6]*bfl(raw.w) + fl[8*c+7]*bfh(raw.w);
      }
      D[t] = s;
    }

    size_t ob = (size_t)(b*NK)*PLANE + (size_t)h*NW + p;
    #pragma unroll
    for (int k = 0; k < NK; ++k) {
      int t0 = 8 - k;
      float cv = (1.f - wfr)*D[t0] + wfr*D[t0+1];
      outg[ob + (size_t)k*PLANE] = cv;
    }
  }
}

extern "C" void kernel_launch(void* const* d_in, const int* in_sizes, int n_in,
                              void* d_out, int out_size, void* d_ws, size_t ws_size,
                              hipStream_t stream) {
  const float* xL   = (const float*)d_in[0];
  const float* xR   = (const float*)d_in[1];
  const float* d0g  = (const float*)d_in[2];
  const float* phig = (const float*)d_in[3];
  float* outg = (float*)d_out;

  const size_t need = 2 * WS_SIDE * sizeof(unsigned short);   // 31,457,280 B
  if (d_ws != nullptr && ws_size >= need) {
    embed_kernel<<<dim3(2*NB*NH), dim3(512), 0, stream>>>(
        xL, xR, phig, (unsigned short*)d_ws);
    cost_kernel<<<dim3(NB*NH), dim3(512), 0, stream>>>(
        (const unsigned short*)d_ws, d0g, outg);
  } else {
    corr_kernel<<<dim3(NB*NH), dim3(1024), 0, stream>>>(xL, xR, d0g, phig, outg);
  }
}

// Round 3
// 155.979 us; speedup vs baseline: 1.0090x; 1.0090x over previous
//
#include <hip/hip_runtime.h>
#include <hip/hip_bf16.h>

#define NB 4
#define NC 128
#define NH 128
#define NW 240
#define NE 64
#define NK 9
#define PLANE (NH*NW)        // 30720: stride between channels
#define CHW (NC*PLANE)
#define XS 244               // xs row stride in ushort (488 B: 8B-aligned, de-conflicted)
#define WS_SIDE ((size_t)NB*NH*NW*64)   // halfs per side in workspace

typedef __attribute__((ext_vector_type(8))) short short8;
typedef __attribute__((ext_vector_type(4))) float f32x4;
typedef __attribute__((ext_vector_type(2))) __fp16 fp16x2;
typedef __attribute__((ext_vector_type(8))) __fp16 fp16x8;

__device__ __forceinline__ unsigned pk2bf(float x, float y){
  __hip_bfloat162 h = __float22bfloat162_rn(make_float2(x, y));  // v_cvt_pk_bf16_f32 on gfx950
  return *(unsigned*)&h;
}
__device__ __forceinline__ unsigned short f2bf(float f){
  unsigned u = __float_as_uint(f);
  u += 0x7fffu + ((u>>16)&1u);           // RNE
  return (unsigned short)(u>>16);
}
__device__ __forceinline__ float bfl(unsigned v){ return __uint_as_float(v<<16); }
__device__ __forceinline__ float bfh(unsigned v){ return __uint_as_float(v & 0xffff0000u); }

// fp16 pack (v_cvt_pkrtz_f16_f32) — builtin returns __fp16 ext-vector
__device__ __forceinline__ unsigned pkh(float x, float y){
  fp16x2 h = __builtin_amdgcn_cvt_pkrtz(x, y);
  return __builtin_bit_cast(unsigned, h);
}
// half2 dot with f32 accumulate (v_dot2_f32_f16)
__device__ __forceinline__ float fdot2u(unsigned a, unsigned b, float c){
#if __has_builtin(__builtin_amdgcn_fdot2)
  return __builtin_amdgcn_fdot2(__builtin_bit_cast(fp16x2,a),
                                __builtin_bit_cast(fp16x2,b), c, false);
#else
  fp16x2 ha = __builtin_bit_cast(fp16x2,a), hb = __builtin_bit_cast(fp16x2,b);
  return c + (float)ha[0]*(float)hb[0] + (float)ha[1]*(float)hb[1];
#endif
}
__device__ __forceinline__ int swz(int r){ return (r ^ (r>>3)) & 7; }

// ======================================================================
// Kernel E: embed both sides. One block per (side, b, h) row.
// grid = 2*NB*NH = 1024, block = 512 (8 waves). LDS = 79,872 B -> 2 blk/CU.
// Staging is fully load-batched (all global loads issued before any cvt/
// ds_write) to create deep MLP: R2 counters showed latency-bound (occ 34%,
// VALU 10%, HBM 23%) with VGPR=52 -> near-zero loads in flight.
// ======================================================================
__global__ __launch_bounds__(512, 4)
void embed_kernel(const float* __restrict__ xL,
                  const float* __restrict__ xR,
                  const float* __restrict__ phig,
                  unsigned short* __restrict__ ws)
{
  __shared__ __attribute__((aligned(16))) unsigned short xs[NC*XS];     // 62,464 B
  __shared__ __attribute__((aligned(16))) unsigned short phis[NE*136];  // 17,408 B

  const int tid  = threadIdx.x;
  const int lane = tid & 63;
  const int wv   = tid >> 6;
  const int bid  = blockIdx.x;
  const int side = bid >> 9;
  const int b    = (bid >> 7) & 3;
  const int h    = bid & 127;
  const float* xg = side ? xR : xL;
  unsigned short* outp = ws + (size_t)side * WS_SIDE;
  const size_t base = (size_t)b*CHW + (size_t)h*NW;
  const int pixbase = (b*NH + h)*NW;

  // ---- issue ALL staging loads first (15 x-row float4 + 4 phi float4) ----
  float4 xr[15];
  int xc[15], xsi[15];
  #pragma unroll
  for (int i = 0; i < 15; ++i) {
    unsigned idx = i*512 + tid;          // dense: 7680 = 128c x 60 float4
    unsigned c = idx / 60u;
    unsigned s = idx - 60u*c;
    xc[i] = c; xsi[i] = s;
    xr[i] = *(const float4*)(xg + base + (size_t)c*PLANE + 4*s);
  }
  float4 pr[4];
  #pragma unroll
  for (int i = 0; i < 4; ++i) {
    int idx = i*512 + tid;
    pr[i] = *(const float4*)(phig + (idx>>5)*128 + 4*(idx&31));
  }
  // ---- convert + LDS writes ----
  #pragma unroll
  for (int i = 0; i < 4; ++i) {
    int idx = i*512 + tid;
    uint2 pk; pk.x = pkh(pr[i].x, pr[i].y); pk.y = pkh(pr[i].z, pr[i].w);
    *(uint2*)&phis[(idx>>5)*136 + 4*(idx&31)] = pk;
  }
  #pragma unroll
  for (int i = 0; i < 15; ++i) {
    uint2 pk; pk.x = pkh(xr[i].x, xr[i].y); pk.y = pkh(xr[i].z, xr[i].w);
    *(uint2*)&xs[xc[i]*XS + 4*xsi[i]] = pk;
  }
  __syncthreads();

  // ---- GEMM + normalize. Wave wv owns N-tiles {wv, wv+8} (15 tiles total) ----
  const int mrow = lane & 15;
  const int kg   = lane >> 4;

  f32x4 acc[2][4];
  #pragma unroll
  for (int tt = 0; tt < 2; ++tt)
    #pragma unroll
    for (int mt = 0; mt < 4; ++mt) acc[tt][mt] = (f32x4){0.f,0.f,0.f,0.f};
  float inv[2] = {0.f, 0.f};

  #pragma unroll
  for (int tt = 0; tt < 2; ++tt) {
    int nt = wv + 8*tt;
    if (nt < 15) {
      const int col = 16*nt + mrow;
      #pragma unroll
      for (int ks = 0; ks < 4; ++ks) {
        const int r0 = 32*ks + 8*kg;
        fp16x8 bv;
        #pragma unroll
        for (int j = 0; j < 8; ++j)
          bv[j] = *(const __fp16*)&xs[(r0 + j)*XS + col];
        #pragma unroll
        for (int mt = 0; mt < 4; ++mt) {
          short8 raw = *(const short8*)&phis[(16*mt + mrow)*136 + 32*ks + 8*kg];
          fp16x8 af = __builtin_bit_cast(fp16x8, raw);
          acc[tt][mt] = __builtin_amdgcn_mfma_f32_16x16x32_f16(af, bv, acc[tt][mt], 0, 0, 0);
        }
      }
      float ss = 0.f;
      #pragma unroll
      for (int mt = 0; mt < 4; ++mt)
        #pragma unroll
        for (int r = 0; r < 4; ++r)
          ss += acc[tt][mt][r]*acc[tt][mt][r];
      ss += __shfl_xor(ss, 16, 64);
      ss += __shfl_xor(ss, 32, 64);
      inv[tt] = 1.f/(sqrtf(ss) + 1e-6f);
    }
  }
  __syncthreads();           // all xs reads done; safe to alias

  // ---- transpose through LDS (aliased over xs) for coalesced stores ----
  unsigned short* Ea = &xs[0];  // 240*64 halfs = 30,720 B <= xs size
  #pragma unroll
  for (int tt = 0; tt < 2; ++tt) {
    int nt = wv + 8*tt;
    if (nt < 15) {
      int n = 16*nt + mrow;
      #pragma unroll
      for (int mt = 0; mt < 4; ++mt) {
        int e0 = 16*mt + 4*kg;
        uint2 pk;
        pk.x = pkh(acc[tt][mt][0]*inv[tt], acc[tt][mt][1]*inv[tt]);
        pk.y = pkh(acc[tt][mt][2]*inv[tt], acc[tt][mt][3]*inv[tt]);
        int pos = n*64 + ((((e0>>3) ^ (n&7))<<3)) + (e0&7);
        *(uint2*)&Ea[pos] = pk;
      }
    }
  }
  __syncthreads();

  // ---- fully coalesced global store: 1920 uint4 ----
  #pragma unroll
  for (int i = 0; i < 4; ++i) {
    int t = i*512 + tid;
    if (t < 1920) {
      int pix = t >> 3, c4 = t & 7;
      uint4 v = *(const uint4*)&Ea[pix*64 + ((c4 ^ (pix&7))<<3)];
      *(uint4*)(outp + (size_t)(pixbase + pix)*64 + c4*8) = v;
    }
  }
}

// ======================================================================
// Kernel C: cost volume. One block per (b,h) row.
// grid = NB*NH = 512, block = 512 (8 waves). LDS = 61,440 B -> 2 blk/CU.
// Batched staging loads; output staged through LDS (aliased over FLb)
// for fully-coalesced float4 stores.
// ======================================================================
__global__ __launch_bounds__(512, 4)
void cost_kernel(const unsigned short* __restrict__ ws,
                 const float* __restrict__ d0g,
                 float* __restrict__ outg)
{
  __shared__ __attribute__((aligned(16))) unsigned short FLb[NW*64];
  __shared__ __attribute__((aligned(16))) unsigned short FRb[NW*64];

  const int tid = threadIdx.x;
  const int b   = blockIdx.x >> 7;
  const int h   = blockIdx.x & 127;
  const int pixbase = (b*NH + h)*NW;
  const unsigned short* FLg = ws;
  const unsigned short* FRg = ws + WS_SIDE;
  const bool act = tid < 480;
  const int p  = tid >> 1;
  const int eh = tid & 1;

  // d0 early (overlaps staging latency)
  float d0v = act ? d0g[pixbase + p] : 0.f;

  // ---- stage FL/FR rows: batch all 8 uint4 loads, then LDS writes ----
  uint4 ra[4], rb[4];
  if (act) {
    #pragma unroll
    for (int i = 0; i < 4; ++i) {
      int u = i*480 + tid;               // 0..1919 dense
      int pix = u >> 3, c4 = u & 7;
      ra[i] = *(const uint4*)(FLg + (size_t)(pixbase + pix)*64 + c4*8);
    }
    #pragma unroll
    for (int i = 0; i < 4; ++i) {
      int u = i*480 + tid;
      int pix = u >> 3, c4 = u & 7;
      rb[i] = *(const uint4*)(FRg + (size_t)(pixbase + pix)*64 + c4*8);
    }
    #pragma unroll
    for (int i = 0; i < 4; ++i) {
      int u = i*480 + tid;
      int pix = u >> 3, c4 = u & 7;
      *(uint4*)&FLb[pix*64 + ((c4 ^ swz(pix))<<3)] = ra[i];
    }
    #pragma unroll
    for (int i = 0; i < 4; ++i) {
      int u = i*480 + tid;
      int pix = u >> 3, c4 = u & 7;
      *(uint4*)&FRb[pix*64 + ((c4 ^ swz(pix))<<3)] = rb[i];
    }
  }
  __syncthreads();

  // ---- per-pixel setup + own half of FL[p] into regs ----
  float wfr = 0.f;
  int jb = 0;
  unsigned fl[16];
  if (act) {
    float xf  = (float)p - d0v;
    float x0  = floorf(xf);
    wfr = xf - x0;
    jb = (int)x0 - 4;
    #pragma unroll
    for (int i = 0; i < 4; ++i) {
      int c4 = 4*eh + i;
      uint4 raw = *(const uint4*)&FLb[p*64 + ((c4 ^ swz(p))<<3)];
      fl[4*i+0]=raw.x; fl[4*i+1]=raw.y; fl[4*i+2]=raw.z; fl[4*i+3]=raw.w;
    }
  }
  __syncthreads();           // ALL FLb reads complete -> safe to alias cvb

  float* cvb = (float*)FLb;  // 9*240*4 = 8,640 B <= 30,720 B

  if (act) {
    float D[10];
    #pragma unroll
    for (int t = 0; t < 10; ++t) {
      int j = jb + t;
      j = j < 0 ? 0 : (j > NW-1 ? NW-1 : j);
      float s = 0.f;
      #pragma unroll
      for (int i = 0; i < 4; ++i) {
        int c4 = 4*eh + i;
        uint4 raw = *(const uint4*)&FRb[j*64 + ((c4 ^ swz(j))<<3)];
        s = fdot2u(fl[4*i+0], raw.x, s);
        s = fdot2u(fl[4*i+1], raw.y, s);
        s = fdot2u(fl[4*i+2], raw.z, s);
        s = fdot2u(fl[4*i+3], raw.w, s);
      }
      D[t] = s;
    }
    // combine the two e-halves (partner lane = tid^1)
    #pragma unroll
    for (int t = 0; t < 10; ++t) D[t] += __shfl_xor(D[t], 1, 64);

    if (eh == 0) {
      #pragma unroll
      for (int k = 0; k < 5; ++k) {
        int t0 = 8 - k;
        cvb[k*NW + p] = (1.f - wfr)*D[t0] + wfr*D[t0+1];
      }
    } else {
      #pragma unroll
      for (int k = 5; k < 9; ++k) {
        int t0 = 8 - k;
        cvb[k*NW + p] = (1.f - wfr)*D[t0] + wfr*D[t0+1];
      }
    }
  }
  __syncthreads();

  // ---- coalesced out store: 540 float4 (9 k-planes x 60) ----
  const size_t ob0 = (size_t)b*NK*PLANE + (size_t)h*NW;
  #pragma unroll
  for (int i = 0; i < 2; ++i) {
    int t = i*512 + tid;
    if (t < 540) {
      int k = t/60, w4 = t - 60*k;
      float4 v = *(const float4*)&cvb[k*NW + 4*w4];
      *(float4*)(outg + ob0 + (size_t)k*PLANE + 4*w4) = v;
    }
  }
}

// ======================================================================
// Fallback: previous verified fused kernel (158 µs) — used if ws too small.
// ======================================================================
__global__ __launch_bounds__(1024, 4)
void corr_kernel(const float* __restrict__ xL,
                 const float* __restrict__ xR,
                 const float* __restrict__ d0g,
                 const float* __restrict__ phig,
                 float* __restrict__ outg)
{
  __shared__ __attribute__((aligned(16))) unsigned short xs[NC*XS];
  __shared__ __attribute__((aligned(16))) unsigned short phis[NE*136];
  __shared__ __attribute__((aligned(16))) unsigned short FLb[NW*64];
  __shared__ __attribute__((aligned(16))) unsigned short FRb[NW*64];

  const int tid  = threadIdx.x;
  const int lane = tid & 63;
  const int wv   = tid >> 6;
  const int b    = blockIdx.x >> 7;
  const int h    = blockIdx.x & 127;
  const size_t base = (size_t)b*CHW + (size_t)h*NW;

  float d0v = 0.f;
  if (tid < NW) d0v = d0g[(b*NH + h)*NW + tid];

  #pragma unroll
  for (int i = 0; i < 2; ++i) {
    int idx = i*1024 + tid;
    int e = idx >> 5, q = idx & 31;
    float4 v = *(const float4*)(phig + e*128 + 4*q);
    uint2 pk; pk.x = pk2bf(v.x, v.y); pk.y = pk2bf(v.z, v.w);
    *(uint2*)&phis[e*136 + 4*q] = pk;
  }

  #pragma unroll
  for (int i = 0; i < 8; ++i) {
    int tau = i*1024 + tid;
    int c = tau >> 6, s = tau & 63;
    if (s < 60) {
      float4 v = *(const float4*)(xL + base + (size_t)c*PLANE + 4*s);
      uint2 pk; pk.x = pk2bf(v.x, v.y); pk.y = pk2bf(v.z, v.w);
      *(uint2*)&xs[c*XS + 4*s] = pk;
    }
  }
  __syncthreads();

  const int mrow = lane & 15;
  const int kg   = lane >> 4;
  const int nt   = wv;

  auto gemm_norm = [&](unsigned short* dst) {
    f32x4 acc[4];
    #pragma unroll
    for (int mt = 0; mt < 4; ++mt) acc[mt] = (f32x4){0.f,0.f,0.f,0.f};

    if (nt < 15) {
      const int col = 16*nt + mrow;
      #pragma unroll
      for (int ks = 0; ks < 4; ++ks) {
        const int r0 = 32*ks + 8*kg;
        short8 bfv;
        #pragma unroll
        for (int j = 0; j < 8; ++j)
          bfv[j] = (short)xs[(r0 + j)*XS + col];
        #pragma unroll
        for (int mt = 0; mt < 4; ++mt) {
          short8 af = *(const short8*)&phis[(16*mt + mrow)*136 + 32*ks + 8*kg];
          acc[mt] = __builtin_amdgcn_mfma_f32_16x16x32_bf16(af, bfv, acc[mt], 0, 0, 0);
        }
      }
      float ss = 0.f;
      #pragma unroll
      for (int mt = 0; mt < 4; ++mt)
        #pragma unroll
        for (int r = 0; r < 4; ++r)
          ss += acc[mt][r]*acc[mt][r];
      ss += __shfl_xor(ss, 16, 64);
      ss += __shfl_xor(ss, 32, 64);
      float inv = 1.f/(sqrtf(ss) + 1e-6f);
      int n = 16*nt + mrow;
      #pragma unroll
      for (int mt = 0; mt < 4; ++mt) {
        int e0 = 16*mt + 4*kg;
        ushort4 pk;
        pk.x = f2bf(acc[mt][0]*inv);
        pk.y = f2bf(acc[mt][1]*inv);
        pk.z = f2bf(acc[mt][2]*inv);
        pk.w = f2bf(acc[mt][3]*inv);
        int pos = n*64 + (((e0>>3) ^ (n&7))<<3) + (e0&7);
        *(ushort4*)&dst[pos] = pk;
      }
    }
  };

  gemm_norm(FLb);
  __syncthreads();

  #pragma unroll
  for (int i = 0; i < 8; ++i) {
    int tau = i*1024 + tid;
    int c = tau >> 6, s = tau & 63;
    if (s < 60) {
      float4 v = *(const float4*)(xR + base + (size_t)c*PLANE + 4*s);
      uint2 pk; pk.x = pk2bf(v.x, v.y); pk.y = pk2bf(v.z, v.w);
      *(uint2*)&xs[c*XS + 4*s] = pk;
    }
  }
  __syncthreads();

  gemm_norm(FRb);
  __syncthreads();

  if (tid < NW) {
    const int p = tid;
    float xf  = (float)p - d0v;
    float x0  = floorf(xf);
    float wfr = xf - x0;
    int jb = (int)x0 - 4;

    float fl[64];
    #pragma unroll
    for (int c = 0; c < 8; ++c) {
      uint4 raw = *(const uint4*)&FLb[p*64 + ((c ^ (p&7))<<3)];
      fl[8*c+0]=bfl(raw.x); fl[8*c+1]=bfh(raw.x);
      fl[8*c+2]=bfl(raw.y); fl[8*c+3]=bfh(raw.y);
      fl[8*c+4]=bfl(raw.z); fl[8*c+5]=bfh(raw.z);
      fl[8*c+6]=bfl(raw.w); fl[8*c+7]=bfh(raw.w);
    }

    float D[10];
    #pragma unroll
    for (int t = 0; t < 10; ++t) {
      int j = jb + t;
      j = j < 0 ? 0 : (j > NW-1 ? NW-1 : j);
      float s = 0.f;
      #pragma unroll
      for (int c = 0; c < 8; ++c) {
        uint4 raw = *(const uint4*)&FRb[j*64 + ((c ^ (j&7))<<3)];
        s += fl[8*c+0]*bfl(raw.x) + fl[8*c+1]*bfh(raw.x)
           + fl[8*c+2]*bfl(raw.y) + fl[8*c+3]*bfh(raw.y)
           + fl[8*c+4]*bfl(raw.z) + fl[8*c+5]*bfh(raw.z)
           + fl[8*c+6]*bfl(raw.w) + fl[8*c+7]*bfh(raw.w);
      }
      D[t] = s;
    }

    size_t ob = (size_t)(b*NK)*PLANE + (size_t)h*NW + p;
    #pragma unroll
    for (int k = 0; k < NK; ++k) {
      int t0 = 8 - k;
      float cv = (1.f - wfr)*D[t0] + wfr*D[t0+1];
      outg[ob + (size_t)k*PLANE] = cv;
    }
  }
}

extern "C" void kernel_launch(void* const* d_in, const int* in_sizes, int n_in,
                              void* d_out, int out_size, void* d_ws, size_t ws_size,
                              hipStream_t stream) {
  const float* xL   = (const float*)d_in[0];
  const float* xR   = (const float*)d_in[1];
  const float* d0g  = (const float*)d_in[2];
  const float* phig = (const float*)d_in[3];
  float* outg = (float*)d_out;

  const size_t need = 2 * WS_SIDE * sizeof(unsigned short);   // 31,457,280 B
  if (d_ws != nullptr && ws_size >= need) {
    embed_kernel<<<dim3(2*NB*NH), dim3(512), 0, stream>>>(
        xL, xR, phig, (unsigned short*)d_ws);
    cost_kernel<<<dim3(NB*NH), dim3(512), 0, stream>>>(
        (const unsigned short*)d_ws, d0g, outg);
  } else {
    corr_kernel<<<dim3(NB*NH), dim3(1024), 0, stream>>>(xL, xR, d0g, phig, outg);
  }
}

// Round 4
// 153.605 us; speedup vs baseline: 1.0246x; 1.0155x over previous
//
#include <hip/hip_runtime.h>
#include <hip/hip_bf16.h>

#define NB 4
#define NC 128
#define NH 128
#define NW 240
#define NE 64
#define NK 9
#define PLANE (NH*NW)        // 30720: stride between channels
#define CHW (NC*PLANE)
#define XS 244               // xs row stride in ushort (488 B: 8B-aligned, de-conflicted)

typedef __attribute__((ext_vector_type(8))) short short8;
typedef __attribute__((ext_vector_type(4))) float f32x4;
typedef __attribute__((ext_vector_type(2))) __fp16 fp16x2;
typedef __attribute__((ext_vector_type(8))) __fp16 fp16x8;

// fp16 pack (v_cvt_pkrtz_f16_f32) — builtin returns __fp16 ext-vector
__device__ __forceinline__ unsigned pkh(float x, float y){
  fp16x2 h = __builtin_amdgcn_cvt_pkrtz(x, y);
  return __builtin_bit_cast(unsigned, h);
}
// half2 dot with f32 accumulate (v_dot2_f32_f16)
__device__ __forceinline__ float fdot2u(unsigned a, unsigned b, float c){
#if __has_builtin(__builtin_amdgcn_fdot2)
  return __builtin_amdgcn_fdot2(__builtin_bit_cast(fp16x2,a),
                                __builtin_bit_cast(fp16x2,b), c, false);
#else
  fp16x2 ha = __builtin_bit_cast(fp16x2,a), hb = __builtin_bit_cast(fp16x2,b);
  return c + (float)ha[0]*(float)hb[0] + (float)ha[1]*(float)hb[1];
#endif
}
__device__ __forceinline__ int swz(int r){ return (r ^ (r>>3)) & 7; }

// ======================================================================
// Fully-fused kernel: one block per (b,h) row. 512 blocks x 1024 threads.
// LDS: xs 62,464 + phis 17,408 + FLb 30,720 = 110,592 B -> 1 block/CU,
// 16 waves (4/SIMD). FRb aliases xs; cvb (fp32 out staging) aliases phis.
// Pipeline: stage(L,phi) | L-GEMM + R-prefetch(regs) | FLfrag->LDS + R->xs
//           | R-GEMM | FRfrag->LDS | cost (4-way e-split, fdot2) | store.
// No workspace traffic, single launch.
// ======================================================================
__global__ __launch_bounds__(1024, 4)
void fused_kernel(const float* __restrict__ xL,
                  const float* __restrict__ xR,
                  const float* __restrict__ d0g,
                  const float* __restrict__ phig,
                  float* __restrict__ outg)
{
  __shared__ __attribute__((aligned(16))) unsigned short xs[NC*XS];     // 62,464 B
  __shared__ __attribute__((aligned(16))) unsigned short phis[NE*136];  // 17,408 B
  __shared__ __attribute__((aligned(16))) unsigned short FLb[NW*64];    // 30,720 B

  const int tid  = threadIdx.x;
  const int lane = tid & 63;
  const int wv   = tid >> 6;
  const int b    = blockIdx.x >> 7;
  const int h    = blockIdx.x & 127;
  const size_t base = (size_t)b*CHW + (size_t)h*NW;
  const int pixbase = (b*NH + h)*NW;

  // d0 for the cost phase — load early, keep in register
  float d0v = (tid < 960) ? d0g[pixbase + (tid >> 2)] : 0.f;

  // ---- phase 1: stage phi + L (all loads batched first) ----
  float4 xr[8];
  #pragma unroll
  for (int i = 0; i < 7; ++i) {
    unsigned idx = i*1024 + tid;            // 7680 = 128c x 60 float4
    unsigned c = idx / 60u, s = idx - 60u*c;
    xr[i] = *(const float4*)(xL + base + (size_t)c*PLANE + 4*s);
  }
  if (tid < 512) {
    unsigned idx = 7168 + tid;
    unsigned c = idx / 60u, s = idx - 60u*c;
    xr[7] = *(const float4*)(xL + base + (size_t)c*PLANE + 4*s);
  }
  float4 pr[2];
  #pragma unroll
  for (int i = 0; i < 2; ++i) {
    int idx = i*1024 + tid;
    pr[i] = *(const float4*)(phig + (idx>>5)*128 + 4*(idx&31));
  }
  #pragma unroll
  for (int i = 0; i < 2; ++i) {
    int idx = i*1024 + tid;
    uint2 pk; pk.x = pkh(pr[i].x, pr[i].y); pk.y = pkh(pr[i].z, pr[i].w);
    *(uint2*)&phis[(idx>>5)*136 + 4*(idx&31)] = pk;
  }
  #pragma unroll
  for (int i = 0; i < 7; ++i) {
    unsigned idx = i*1024 + tid;
    unsigned c = idx / 60u, s = idx - 60u*c;
    uint2 pk; pk.x = pkh(xr[i].x, xr[i].y); pk.y = pkh(xr[i].z, xr[i].w);
    *(uint2*)&xs[c*XS + 4*s] = pk;
  }
  if (tid < 512) {
    unsigned idx = 7168 + tid;
    unsigned c = idx / 60u, s = idx - 60u*c;
    uint2 pk; pk.x = pkh(xr[7].x, xr[7].y); pk.y = pkh(xr[7].z, xr[7].w);
    *(uint2*)&xs[c*XS + 4*s] = pk;
  }
  __syncthreads();

  // ---- phase 2: R prefetch into registers (flies during L-GEMM) ----
  float4 xrR[8];
  #pragma unroll
  for (int i = 0; i < 7; ++i) {
    unsigned idx = i*1024 + tid;
    unsigned c = idx / 60u, s = idx - 60u*c;
    xrR[i] = *(const float4*)(xR + base + (size_t)c*PLANE + 4*s);
  }
  if (tid < 512) {
    unsigned idx = 7168 + tid;
    unsigned c = idx / 60u, s = idx - 60u*c;
    xrR[7] = *(const float4*)(xR + base + (size_t)c*PLANE + 4*s);
  }

  // ---- L-GEMM + normalize -> packed frags in regs ----
  const int mrow = lane & 15;
  const int kg   = lane >> 4;
  const int nt   = wv;                       // 16 waves, nt<15 active
  const int n    = 16*nt + mrow;             // pixel owned in epilogue

  uint2 flpk[4];
  {
    f32x4 acc[4];
    #pragma unroll
    for (int mt = 0; mt < 4; ++mt) acc[mt] = (f32x4){0.f,0.f,0.f,0.f};
    if (nt < 15) {
      const int col = n;
      #pragma unroll
      for (int ks = 0; ks < 4; ++ks) {
        const int r0 = 32*ks + 8*kg;
        fp16x8 bv;
        #pragma unroll
        for (int j = 0; j < 8; ++j)
          bv[j] = *(const __fp16*)&xs[(r0 + j)*XS + col];
        #pragma unroll
        for (int mt = 0; mt < 4; ++mt) {
          short8 raw = *(const short8*)&phis[(16*mt + mrow)*136 + 32*ks + 8*kg];
          fp16x8 af = __builtin_bit_cast(fp16x8, raw);
          acc[mt] = __builtin_amdgcn_mfma_f32_16x16x32_f16(af, bv, acc[mt], 0, 0, 0);
        }
      }
      float ss = 0.f;
      #pragma unroll
      for (int mt = 0; mt < 4; ++mt)
        #pragma unroll
        for (int r = 0; r < 4; ++r)
          ss += acc[mt][r]*acc[mt][r];
      ss += __shfl_xor(ss, 16, 64);
      ss += __shfl_xor(ss, 32, 64);
      float inv = 1.f/(sqrtf(ss) + 1e-6f);
      #pragma unroll
      for (int mt = 0; mt < 4; ++mt) {
        flpk[mt].x = pkh(acc[mt][0]*inv, acc[mt][1]*inv);
        flpk[mt].y = pkh(acc[mt][2]*inv, acc[mt][3]*inv);
      }
    }
  }
  __syncthreads();           // all xs(L) reads done

  // ---- phase 3: FL frags -> FLb (swizzled pixel-major) + R -> xs ----
  if (nt < 15) {
    #pragma unroll
    for (int mt = 0; mt < 4; ++mt) {
      int e0 = 16*mt + 4*kg;
      int pos = n*64 + (((e0>>3) ^ swz(n))<<3) + (e0&7);
      *(uint2*)&FLb[pos] = flpk[mt];
    }
  }
  #pragma unroll
  for (int i = 0; i < 7; ++i) {
    unsigned idx = i*1024 + tid;
    unsigned c = idx / 60u, s = idx - 60u*c;
    uint2 pk; pk.x = pkh(xrR[i].x, xrR[i].y); pk.y = pkh(xrR[i].z, xrR[i].w);
    *(uint2*)&xs[c*XS + 4*s] = pk;
  }
  if (tid < 512) {
    unsigned idx = 7168 + tid;
    unsigned c = idx / 60u, s = idx - 60u*c;
    uint2 pk; pk.x = pkh(xrR[7].x, xrR[7].y); pk.y = pkh(xrR[7].z, xrR[7].w);
    *(uint2*)&xs[c*XS + 4*s] = pk;
  }
  __syncthreads();

  // ---- phase 4: R-GEMM + normalize -> packed frags in regs ----
  uint2 frpk[4];
  {
    f32x4 acc[4];
    #pragma unroll
    for (int mt = 0; mt < 4; ++mt) acc[mt] = (f32x4){0.f,0.f,0.f,0.f};
    if (nt < 15) {
      const int col = n;
      #pragma unroll
      for (int ks = 0; ks < 4; ++ks) {
        const int r0 = 32*ks + 8*kg;
        fp16x8 bv;
        #pragma unroll
        for (int j = 0; j < 8; ++j)
          bv[j] = *(const __fp16*)&xs[(r0 + j)*XS + col];
        #pragma unroll
        for (int mt = 0; mt < 4; ++mt) {
          short8 raw = *(const short8*)&phis[(16*mt + mrow)*136 + 32*ks + 8*kg];
          fp16x8 af = __builtin_bit_cast(fp16x8, raw);
          acc[mt] = __builtin_amdgcn_mfma_f32_16x16x32_f16(af, bv, acc[mt], 0, 0, 0);
        }
      }
      float ss = 0.f;
      #pragma unroll
      for (int mt = 0; mt < 4; ++mt)
        #pragma unroll
        for (int r = 0; r < 4; ++r)
          ss += acc[mt][r]*acc[mt][r];
      ss += __shfl_xor(ss, 16, 64);
      ss += __shfl_xor(ss, 32, 64);
      float inv = 1.f/(sqrtf(ss) + 1e-6f);
      #pragma unroll
      for (int mt = 0; mt < 4; ++mt) {
        frpk[mt].x = pkh(acc[mt][0]*inv, acc[mt][1]*inv);
        frpk[mt].y = pkh(acc[mt][2]*inv, acc[mt][3]*inv);
      }
    }
  }
  __syncthreads();           // all xs(R)/phis reads done -> safe to alias

  // ---- phase 5: FR frags -> FRb (aliases xs) ----
  unsigned short* FRb = &xs[0];              // 30,720 B used
  if (nt < 15) {
    #pragma unroll
    for (int mt = 0; mt < 4; ++mt) {
      int e0 = 16*mt + 4*kg;
      int pos = n*64 + (((e0>>3) ^ swz(n))<<3) + (e0&7);
      *(uint2*)&FRb[pos] = frpk[mt];
    }
  }
  __syncthreads();

  // ---- phase 6: cost (p = tid>>2, 4-way e-split, fdot2) ----
  float* cvb = (float*)phis;                 // 9*240*4 = 8,640 B <= 17,408
  if (tid < 960) {
    const int p  = tid >> 2;
    const int eh = tid & 3;
    float xf  = (float)p - d0v;
    float x0  = floorf(xf);
    float wfr = xf - x0;
    int jb = (int)x0 - 4;

    unsigned fl[8];
    #pragma unroll
    for (int i = 0; i < 2; ++i) {
      int c4 = 2*eh + i;
      uint4 raw = *(const uint4*)&FLb[p*64 + ((c4 ^ swz(p))<<3)];
      fl[4*i+0]=raw.x; fl[4*i+1]=raw.y; fl[4*i+2]=raw.z; fl[4*i+3]=raw.w;
    }

    float D[10];
    #pragma unroll
    for (int t = 0; t < 10; ++t) {
      int j = jb + t;
      j = j < 0 ? 0 : (j > NW-1 ? NW-1 : j);
      float s = 0.f;
      #pragma unroll
      for (int i = 0; i < 2; ++i) {
        int c4 = 2*eh + i;
        uint4 raw = *(const uint4*)&FRb[j*64 + ((c4 ^ swz(j))<<3)];
        s = fdot2u(fl[4*i+0], raw.x, s);
        s = fdot2u(fl[4*i+1], raw.y, s);
        s = fdot2u(fl[4*i+2], raw.z, s);
        s = fdot2u(fl[4*i+3], raw.w, s);
      }
      D[t] = s;
    }
    #pragma unroll
    for (int t = 0; t < 10; ++t) {
      D[t] += __shfl_xor(D[t], 1, 64);
      D[t] += __shfl_xor(D[t], 2, 64);
    }

    #define WK(k) { const int t0 = 8-(k); cvb[(k)*NW + p] = (1.f - wfr)*D[t0] + wfr*D[t0+1]; }
    if      (eh == 0) { WK(0) WK(1) WK(2) }
    else if (eh == 1) { WK(3) WK(4) }
    else if (eh == 2) { WK(5) WK(6) }
    else              { WK(7) WK(8) }
    #undef WK
  }
  __syncthreads();

  // ---- phase 7: coalesced out store: 540 float4 (9 k-planes x 60) ----
  if (tid < 540) {
    int k = tid/60, w4 = tid - 60*k;
    float4 v = *(const float4*)&cvb[k*NW + 4*w4];
    *(float4*)(outg + (size_t)b*NK*PLANE + (size_t)h*NW + (size_t)k*PLANE + 4*w4) = v;
  }
}

extern "C" void kernel_launch(void* const* d_in, const int* in_sizes, int n_in,
                              void* d_out, int out_size, void* d_ws, size_t ws_size,
                              hipStream_t stream) {
  const float* xL   = (const float*)d_in[0];
  const float* xR   = (const float*)d_in[1];
  const float* d0g  = (const float*)d_in[2];
  const float* phig = (const float*)d_in[3];
  float* outg = (float*)d_out;
  fused_kernel<<<dim3(NB*NH), dim3(1024), 0, stream>>>(xL, xR, d0g, phig, outg);
}

// Round 5
// 148.081 us; speedup vs baseline: 1.0628x; 1.0373x over previous
//
#include <hip/hip_runtime.h>
#include <hip/hip_bf16.h>

#define NB 4
#define NC 128
#define NH 128
#define NW 240
#define NE 64
#define NK 9
#define PLANE (NH*NW)        // 30720: stride between channels
#define CHW (NC*PLANE)
#define XS 244               // xs row stride in ushort (488 B: 8B-aligned, de-conflicted)

typedef __attribute__((ext_vector_type(8))) short short8;
typedef __attribute__((ext_vector_type(4))) float f32x4;
typedef __attribute__((ext_vector_type(2))) __fp16 fp16x2;
typedef __attribute__((ext_vector_type(8))) __fp16 fp16x8;

__device__ __forceinline__ unsigned pkh(float x, float y){
  fp16x2 h = __builtin_amdgcn_cvt_pkrtz(x, y);
  return __builtin_bit_cast(unsigned, h);
}
__device__ __forceinline__ float fdot2u(unsigned a, unsigned b, float c){
#if __has_builtin(__builtin_amdgcn_fdot2)
  return __builtin_amdgcn_fdot2(__builtin_bit_cast(fp16x2,a),
                                __builtin_bit_cast(fp16x2,b), c, false);
#else
  fp16x2 ha = __builtin_bit_cast(fp16x2,a), hb = __builtin_bit_cast(fp16x2,b);
  return c + (float)ha[0]*(float)hb[0] + (float)ha[1]*(float)hb[1];
#endif
}
__device__ __forceinline__ int swz(int r){ return (r ^ (r>>3)) & 7; }

// ======================================================================
// Fused, C-chunked kernel: one block per (b,h) row. 512 blocks x 1024 thr.
// LDS: xs 31,232 (64ch chunk; FRb aliases) + phis 17,408 (cvb aliases)
//      + FLb 30,720 = 79,360 B -> 2 blocks/CU, 32 waves/CU (full occ).
// GEMM accumulates over two 64-channel chunks; each chunk's global loads
// are prefetched into registers under the previous chunk's MFMA.
// ======================================================================
__global__ __launch_bounds__(1024, 8)
void fused_kernel(const float* __restrict__ xL,
                  const float* __restrict__ xR,
                  const float* __restrict__ d0g,
                  const float* __restrict__ phig,
                  float* __restrict__ outg)
{
  __shared__ __attribute__((aligned(16))) unsigned short xs[64*XS];     // 31,232 B
  __shared__ __attribute__((aligned(16))) unsigned short phis[NE*136];  // 17,408 B
  __shared__ __attribute__((aligned(16))) unsigned short FLb[NW*64];    // 30,720 B

  const int tid  = threadIdx.x;
  const int lane = tid & 63;
  const int wv   = tid >> 6;
  const int b    = blockIdx.x >> 7;
  const int h    = blockIdx.x & 127;
  const size_t base = (size_t)b*CHW + (size_t)h*NW;
  const int pixbase = (b*NH + h)*NW;

  const int mrow = lane & 15;
  const int kg   = lane >> 4;
  const int nt   = wv;                 // 16 waves, nt<15 active
  const int n    = 16*nt + mrow;       // owned pixel column

  // d0 for the cost phase — load early, keep in register
  float d0v = (tid < 960) ? d0g[pixbase + (tid >> 2)] : 0.f;

  // ---- staging helpers: 64-channel chunk = 3840 float4, 960 thr x 4 ----
  auto load_chunk = [&](const float* __restrict__ xg, int ch, float4 (&r)[4]) {
    if (tid < 960) {
      #pragma unroll
      for (int i = 0; i < 4; ++i) {
        unsigned idx = i*960 + tid;
        unsigned c = idx / 60u, s = idx - 60u*c;
        r[i] = *(const float4*)(xg + base + (size_t)(64*ch + c)*PLANE + 4*s);
      }
    }
  };
  auto write_chunk = [&](float4 (&r)[4]) {
    if (tid < 960) {
      #pragma unroll
      for (int i = 0; i < 4; ++i) {
        unsigned idx = i*960 + tid;
        unsigned c = idx / 60u, s = idx - 60u*c;
        uint2 pk; pk.x = pkh(r[i].x, r[i].y); pk.y = pkh(r[i].z, r[i].w);
        *(uint2*)&xs[c*XS + 4*s] = pk;
      }
    }
  };
  // ---- GEMM over one chunk (accumulate) ----
  auto gemm_chunk = [&](f32x4 (&acc)[4], int ch) {
    if (nt < 15) {
      #pragma unroll
      for (int ks = 0; ks < 2; ++ks) {
        const int r0 = 32*ks + 8*kg;
        fp16x8 bv;
        #pragma unroll
        for (int j = 0; j < 8; ++j)
          bv[j] = *(const __fp16*)&xs[(r0 + j)*XS + n];
        #pragma unroll
        for (int mt = 0; mt < 4; ++mt) {
          short8 raw = *(const short8*)&phis[(16*mt + mrow)*136 + 64*ch + 32*ks + 8*kg];
          fp16x8 af = __builtin_bit_cast(fp16x8, raw);
          acc[mt] = __builtin_amdgcn_mfma_f32_16x16x32_f16(af, bv, acc[mt], 0, 0, 0);
        }
      }
    }
  };
  auto norm_pack = [&](f32x4 (&acc)[4], uint2 (&pk)[4]) {
    float ss = 0.f;
    #pragma unroll
    for (int mt = 0; mt < 4; ++mt)
      #pragma unroll
      for (int r = 0; r < 4; ++r)
        ss += acc[mt][r]*acc[mt][r];
    ss += __shfl_xor(ss, 16, 64);
    ss += __shfl_xor(ss, 32, 64);
    float inv = 1.f/(sqrtf(ss) + 1e-6f);
    #pragma unroll
    for (int mt = 0; mt < 4; ++mt) {
      pk[mt].x = pkh(acc[mt][0]*inv, acc[mt][1]*inv);
      pk[mt].y = pkh(acc[mt][2]*inv, acc[mt][3]*inv);
    }
  };

  // ---- prologue: phi + L.ch0 ----
  float4 st[4];
  load_chunk(xL, 0, st);
  float4 pr[2];
  #pragma unroll
  for (int i = 0; i < 2; ++i) {
    int idx = i*1024 + tid;
    pr[i] = *(const float4*)(phig + (idx>>5)*128 + 4*(idx&31));
  }
  #pragma unroll
  for (int i = 0; i < 2; ++i) {
    int idx = i*1024 + tid;
    uint2 pk; pk.x = pkh(pr[i].x, pr[i].y); pk.y = pkh(pr[i].z, pr[i].w);
    *(uint2*)&phis[(idx>>5)*136 + 4*(idx&31)] = pk;
  }
  write_chunk(st);
  __syncthreads();                     // xs = L.ch0

  f32x4 accL[4];
  #pragma unroll
  for (int mt = 0; mt < 4; ++mt) accL[mt] = (f32x4){0.f,0.f,0.f,0.f};

  load_chunk(xL, 1, st);               // in flight under GEMM
  gemm_chunk(accL, 0);
  __syncthreads();                     // xs reads done
  write_chunk(st);
  __syncthreads();                     // xs = L.ch1

  load_chunk(xR, 0, st);
  gemm_chunk(accL, 1);
  uint2 flpk[4];
  norm_pack(accL, flpk);
  if (nt < 15) {
    #pragma unroll
    for (int mt = 0; mt < 4; ++mt) {
      int e0 = 16*mt + 4*kg;
      int pos = n*64 + (((e0>>3) ^ swz(n))<<3) + (e0&7);
      *(uint2*)&FLb[pos] = flpk[mt];
    }
  }
  __syncthreads();                     // xs reads done
  write_chunk(st);
  __syncthreads();                     // xs = R.ch0

  f32x4 accR[4];
  #pragma unroll
  for (int mt = 0; mt < 4; ++mt) accR[mt] = (f32x4){0.f,0.f,0.f,0.f};

  load_chunk(xR, 1, st);
  gemm_chunk(accR, 0);
  __syncthreads();                     // xs reads done
  write_chunk(st);
  __syncthreads();                     // xs = R.ch1

  gemm_chunk(accR, 1);
  uint2 frpk[4];
  norm_pack(accR, frpk);
  __syncthreads();                     // all xs/phis reads done -> alias

  // ---- FR frags -> FRb (aliases xs) ----
  unsigned short* FRb = &xs[0];        // 30,720 B used
  if (nt < 15) {
    #pragma unroll
    for (int mt = 0; mt < 4; ++mt) {
      int e0 = 16*mt + 4*kg;
      int pos = n*64 + (((e0>>3) ^ swz(n))<<3) + (e0&7);
      *(uint2*)&FRb[pos] = frpk[mt];
    }
  }
  __syncthreads();

  // ---- cost (p = tid>>2, 4-way e-split, fdot2) ----
  float* cvb = (float*)phis;           // 9*240*4 = 8,640 B <= 17,408
  if (tid < 960) {
    const int p  = tid >> 2;
    const int eh = tid & 3;
    float xf  = (float)p - d0v;
    float x0  = floorf(xf);
    float wfr = xf - x0;
    int jb = (int)x0 - 4;

    unsigned fl[8];
    #pragma unroll
    for (int i = 0; i < 2; ++i) {
      int c4 = 2*eh + i;
      uint4 raw = *(const uint4*)&FLb[p*64 + ((c4 ^ swz(p))<<3)];
      fl[4*i+0]=raw.x; fl[4*i+1]=raw.y; fl[4*i+2]=raw.z; fl[4*i+3]=raw.w;
    }

    float D[10];
    #pragma unroll
    for (int t = 0; t < 10; ++t) {
      int j = jb + t;
      j = j < 0 ? 0 : (j > NW-1 ? NW-1 : j);
      float s = 0.f;
      #pragma unroll
      for (int i = 0; i < 2; ++i) {
        int c4 = 2*eh + i;
        uint4 raw = *(const uint4*)&FRb[j*64 + ((c4 ^ swz(j))<<3)];
        s = fdot2u(fl[4*i+0], raw.x, s);
        s = fdot2u(fl[4*i+1], raw.y, s);
        s = fdot2u(fl[4*i+2], raw.z, s);
        s = fdot2u(fl[4*i+3], raw.w, s);
      }
      D[t] = s;
    }
    #pragma unroll
    for (int t = 0; t < 10; ++t) {
      D[t] += __shfl_xor(D[t], 1, 64);
      D[t] += __shfl_xor(D[t], 2, 64);
    }

    #define WK(k) { const int t0 = 8-(k); cvb[(k)*NW + p] = (1.f - wfr)*D[t0] + wfr*D[t0+1]; }
    if      (eh == 0) { WK(0) WK(1) WK(2) }
    else if (eh == 1) { WK(3) WK(4) }
    else if (eh == 2) { WK(5) WK(6) }
    else              { WK(7) WK(8) }
    #undef WK
  }
  __syncthreads();

  // ---- coalesced out store: 540 float4 (9 k-planes x 60) ----
  if (tid < 540) {
    int k = tid/60, w4 = tid - 60*k;
    float4 v = *(const float4*)&cvb[k*NW + 4*w4];
    *(float4*)(outg + (size_t)b*NK*PLANE + (size_t)h*NW + (size_t)k*PLANE + 4*w4) = v;
  }
}

extern "C" void kernel_launch(void* const* d_in, const int* in_sizes, int n_in,
                              void* d_out, int out_size, void* d_ws, size_t ws_size,
                              hipStream_t stream) {
  const float* xL   = (const float*)d_in[0];
  const float* xR   = (const float*)d_in[1];
  const float* d0g  = (const float*)d_in[2];
  const float* phig = (const float*)d_in[3];
  float* outg = (float*)d_out;
  fused_kernel<<<dim3(NB*NH), dim3(1024), 0, stream>>>(xL, xR, d0g, phig, outg);
}